// Round 5
// baseline (153.154 us; speedup 1.0000x reference)
//
#include <hip/hip_runtime.h>
#include <stdint.h>

#define BB 16
#define TT 4096
#define DDIM 512
#define KK 128
#define TCB 128            // t-rows per chunk
#define NCB (TT / TCB)     // 32 chunks
#define PI_F 3.14159265358979323846f

typedef unsigned short u16;
typedef __attribute__((ext_vector_type(8))) short short8;
typedef __attribute__((ext_vector_type(4))) float f32x4;

__device__ __forceinline__ uint32_t cvt_bf16_rn(float f) {
  uint32_t u = __float_as_uint(f);
  return (u + 0x7FFFu + ((u >> 16) & 1u)) >> 16;
}
__device__ __forceinline__ void split2(float a, float b, uint32_t& h, uint32_t& l) {
  uint32_t ha = cvt_bf16_rn(a), hb = cvt_bf16_rn(b);
  float ra = a - __uint_as_float(ha << 16);
  float rb = b - __uint_as_float(hb << 16);
  h = ha | (hb << 16);
  l = cvt_bf16_rn(ra) | (cvt_bf16_rn(rb) << 16);
}
__device__ __forceinline__ void split8v(const float4 f0, const float4 f1, uint4& h, uint4& l) {
  split2(f0.x, f0.y, h.x, l.x);
  split2(f0.z, f0.w, h.y, l.y);
  split2(f1.x, f1.y, h.z, l.z);
  split2(f1.z, f1.w, h.w, l.w);
}
__device__ __forceinline__ void gload_lds16(const void* g, void* l) {
  __builtin_amdgcn_global_load_lds(
      (const __attribute__((address_space(1))) void*)g,
      (__attribute__((address_space(3))) void*)l, 16, 0, 0);
}

// ---------------- kernel 0: fused prep (wpack | ct | params) ----------------
__global__ __launch_bounds__(256) void k_prep(
    const float* __restrict__ W, const float* __restrict__ u_sn,
    const float* __restrict__ s_real_raw, const float* __restrict__ s_imag,
    const float* __restrict__ bias, const float* __restrict__ b_log,
    const float* __restrict__ dt,
    float* __restrict__ params, u16* __restrict__ Wp, float* __restrict__ ct) {
  int gb = blockIdx.x;
  int tid = threadIdx.x;
  if (gb < 64) {
    int idx = gb * 256 + tid;
    int k = idx >> 7;
    int d = (idx & 127) * 4;
    float4 v = *(const float4*)&W[(size_t)k * DDIM + d];
    uint32_t h0, l0, h1, l1;
    split2(v.x, v.y, h0, l0);
    split2(v.z, v.w, h1, l1);
    int tile = d >> 6, dl = d & 63;
    int slot = (dl >> 3) ^ (k & 7);
    int e = dl & 7;
    size_t base = (size_t)tile * 16384 + k * 64 + slot * 8 + e;
    *(uint32_t*)&Wp[base] = h0;
    *(uint32_t*)&Wp[base + 2] = h1;
    *(uint32_t*)&Wp[base + 8192] = l0;
    *(uint32_t*)&Wp[base + 8192 + 2] = l1;
  } else if (gb < 80) {
    __shared__ float sc[256];
    int b = gb - 64;
    const float* row = dt + (size_t)b * TT;
    float* orow = ct + (size_t)b * TT;
    float loc[16];
    float s = 0.f;
    int base = tid * 16;
    for (int i = 0; i < 16; ++i) { s += row[base + i]; loc[i] = s; }
    sc[tid] = s;
    __syncthreads();
    for (int off = 1; off < 256; off <<= 1) {
      float v = (tid >= off) ? sc[tid - off] : 0.f;
      __syncthreads();
      sc[tid] += v;
      __syncthreads();
    }
    float excl = sc[tid] - s;
    for (int i = 0; i < 16; ++i) orow[base + i] = excl + loc[i];
  } else {
    __shared__ float su[KK];
    __shared__ float sv[DDIM];
    __shared__ float red[4];
    __shared__ float s_sig;
    if (tid < KK) su[tid] = u_sn[tid];
    __syncthreads();
    for (int rep = 0; rep < 2; ++rep) {
      int d = tid + rep * 256;
      float acc = 0.f;
      for (int k = 0; k < KK; ++k) acc += W[k * DDIM + d] * su[k];
      sv[d] = acc;
    }
    __syncthreads();
    float nn = 0.f;
    for (int rep = 0; rep < 2; ++rep) { float v = sv[tid + rep * 256]; nn += v * v; }
    for (int off = 32; off > 0; off >>= 1) nn += __shfl_down(nn, off, 64);
    if ((tid & 63) == 0) red[tid >> 6] = nn;
    __syncthreads();
    float vn2 = red[0] + red[1] + red[2] + red[3];
    __syncthreads();
    float vinv = 1.f / (sqrtf(vn2) + 1e-6f);
    for (int rep = 0; rep < 2; ++rep) sv[tid + rep * 256] *= vinv;
    __syncthreads();
    float wv = 0.f;
    if (tid < KK) {
      const float* wrow = W + (size_t)tid * DDIM;
      for (int d = 0; d < DDIM; ++d) wv += wrow[d] * sv[d];
    }
    float q = wv * wv;
    for (int off = 32; off > 0; off >>= 1) q += __shfl_down(q, off, 64);
    if ((tid & 63) == 0) red[tid >> 6] = q;
    __syncthreads();
    if (tid == 0) {
      float wn2 = red[0] + red[1] + red[2] + red[3];
      s_sig = wn2 / (sqrtf(wn2) + 1e-6f);
    }
    __syncthreads();
    if (tid < KK) {
      float inv_sigma = 1.f / s_sig;
      float sr = s_real_raw[tid];
      float alpha = ((sr > 20.f) ? sr : log1pf(expf(sr))) + 1e-6f;
      float om = fminf(fmaxf(s_imag[tid], -PI_F), PI_F);
      float bg = expf(b_log[tid]);
      params[tid] = alpha;
      params[KK + tid] = om;
      params[2 * KK + tid] = bg * inv_sigma;
      params[3 * KK + tid] = bg * bias[tid];
    }
  }
}

// ---------------- kernel 1: fused GEMM + scan + grid-barrier + finalize ----------------
// D[t][k]: A = x-tile (bf16 hi/lo in LDS), B = W-tile (pre-packed, global_load_lds).
// Sync: csum published via RELAXED agent atomics (memory-side, no L2 inv);
// one manual grid barrier (1 poller/block, relaxed polls + s_sleep, fences only at edges).
__global__ __launch_bounds__(512, 4) void k_fused(
    const float* __restrict__ x, const u16* __restrict__ Wp,
    const float* __restrict__ dt, const float* __restrict__ ct,
    const float* __restrict__ params, float* __restrict__ out,
    float* __restrict__ csum_re, float* __restrict__ csum_im,
    int* __restrict__ counter) {
  __shared__ __align__(16) u16 smem[32768];   // 64 KB
  u16* xhi = smem;            // [128][64]
  u16* xlo = smem + 8192;
  u16* whi = smem + 16384;    // [128][64]
  u16* wlo = smem + 24576;

  const int chunk = blockIdx.x, b = blockIdx.y;
  const int tid = threadIdx.x;
  const int wv = tid >> 6, l = tid & 63;
  const int lm = l & 15, lg = l >> 4;
  const int kw = wv & 1, tw = wv >> 1;
  const int t0 = chunk * TCB;

  const int xr = tid >> 2, xq = (tid & 3) * 16;
  const size_t xbase = ((size_t)b * TT + t0 + xr) * DDIM + xq;
  const char* wsrc0 = (const char*)Wp + (size_t)wv * 1024 + (size_t)l * 16;
  char* wdst0 = (char*)whi + wv * 1024;
  const int xs0 = ((xq >> 3) ^ (xr & 7)) * 8;
  const int xs1 = (((xq >> 3) + 1) ^ (xr & 7)) * 8;

  f32x4 acc[2][4];
#pragma unroll
  for (int m = 0; m < 2; ++m)
#pragma unroll
    for (int n = 0; n < 4; ++n) acc[m][n] = (f32x4)(0.0f);

  for (int d0 = 0; d0 < DDIM; d0 += 64) {
    const char* wsg = wsrc0 + (size_t)(d0 >> 6) * 32768;
#pragma unroll
    for (int r = 0; r < 4; ++r)
      gload_lds16(wsg + r * 8192, wdst0 + r * 8192);
    const float* xp = x + xbase + d0;
    float4 f0 = *(const float4*)(xp + 0);
    float4 f1 = *(const float4*)(xp + 4);
    float4 f2 = *(const float4*)(xp + 8);
    float4 f3 = *(const float4*)(xp + 12);
    uint4 h0, lo0, h1, lo1;
    split8v(f0, f1, h0, lo0);
    split8v(f2, f3, h1, lo1);
    *(uint4*)&xhi[xr * 64 + xs0] = h0;
    *(uint4*)&xhi[xr * 64 + xs1] = h1;
    *(uint4*)&xlo[xr * 64 + xs0] = lo0;
    *(uint4*)&xlo[xr * 64 + xs1] = lo1;
    __syncthreads();
#pragma unroll
    for (int ks = 0; ks < 2; ++ks) {
      short8 fa_h[2], fa_l[2], fb_h[4], fb_l[4];
#pragma unroll
      for (int m = 0; m < 2; ++m) {
        int row = tw * 32 + m * 16 + lm;
        int sw = ((ks * 4 + lg) ^ (row & 7)) * 8;
        fa_h[m] = *(const short8*)&xhi[row * 64 + sw];
        fa_l[m] = *(const short8*)&xlo[row * 64 + sw];
      }
#pragma unroll
      for (int n = 0; n < 4; ++n) {
        int row = kw * 64 + n * 16 + lm;
        int sw = ((ks * 4 + lg) ^ (row & 7)) * 8;
        fb_h[n] = *(const short8*)&whi[row * 64 + sw];
        fb_l[n] = *(const short8*)&wlo[row * 64 + sw];
      }
#pragma unroll
      for (int m = 0; m < 2; ++m)
#pragma unroll
        for (int n = 0; n < 4; ++n) {
          acc[m][n] = __builtin_amdgcn_mfma_f32_16x16x32_bf16(fa_h[m], fb_h[n], acc[m][n], 0, 0, 0);
          acc[m][n] = __builtin_amdgcn_mfma_f32_16x16x32_bf16(fa_l[m], fb_h[n], acc[m][n], 0, 0, 0);
          acc[m][n] = __builtin_amdgcn_mfma_f32_16x16x32_bf16(fa_h[m], fb_l[n], acc[m][n], 0, 0, 0);
        }
    }
    __syncthreads();
  }

  // ---- params / dt / ct
  float pal[4], pom[4], pc1[4], pc2[4];
#pragma unroll
  for (int n = 0; n < 4; ++n) {
    int k = kw * 64 + n * 16 + lm;
    pal[n] = params[k];
    pom[n] = params[KK + k];
    pc1[n] = params[2 * KK + k];
    pc2[n] = params[3 * KK + k];
  }
  float dtv[2][4], ctv[2][4];
#pragma unroll
  for (int m = 0; m < 2; ++m)
#pragma unroll
    for (int r = 0; r < 4; ++r) {
      int t = t0 + tw * 32 + m * 16 + lg * 4 + r;
      dtv[m][r] = dt[(size_t)b * TT + t];
      ctv[m][r] = ct[(size_t)b * TT + t];
    }
  // ---- transform g -> w
  float vre[2][4][4], vim[2][4][4];
#pragma unroll
  for (int m = 0; m < 2; ++m)
#pragma unroll
    for (int n = 0; n < 4; ++n)
#pragma unroll
      for (int r = 0; r < 4; ++r) {
        float g = acc[m][n][r];
        float a = pal[n] * dtv[m][r];
        float omr = a * (1.f - a * (0.5f - a * (1.f / 6.f)));  // 1 - exp(-a)
        float itv = omr * (pc1[n] * g + pc2[n]);
        float e = __expf(pal[n] * ctv[m][r]);
        float sn, cs;
        __sincosf(pom[n] * ctv[m][r], &sn, &cs);
        vre[m][n][r] = itv * e * cs;
        vim[m][n][r] = -(itv * e) * sn;
      }
  // ---- in-wave scan over t
  float carR[4], carI[4];
#pragma unroll
  for (int n = 0; n < 4; ++n) {
    float cr = 0.f, ci = 0.f;
#pragma unroll
    for (int m = 0; m < 2; ++m) {
      vre[m][n][1] += vre[m][n][0];
      vre[m][n][2] += vre[m][n][1];
      vre[m][n][3] += vre[m][n][2];
      vim[m][n][1] += vim[m][n][0];
      vim[m][n][2] += vim[m][n][1];
      vim[m][n][3] += vim[m][n][2];
      float ar = vre[m][n][3], ai = vim[m][n][3];
      float tr = ar, ti = ai;
      float ur = __shfl_up(ar, 16, 64);
      float ui = __shfl_up(ai, 16, 64);
      if (lg >= 1) { ar += ur; ai += ui; }
      ur = __shfl_up(ar, 32, 64);
      ui = __shfl_up(ai, 32, 64);
      if (lg >= 2) { ar += ur; ai += ui; }
      float exr = ar - tr + cr;
      float exi = ai - ti + ci;
#pragma unroll
      for (int r = 0; r < 4; ++r) { vre[m][n][r] += exr; vim[m][n][r] += exi; }
      cr += __shfl(ar, 48 + lm, 64);
      ci += __shfl(ai, 48 + lm, 64);
    }
    carR[n] = cr; carI[n] = ci;
  }
  // ---- cross-wave (tw) carry via LDS
  float* totr = (float*)smem;         // [4][128]
  float* toti = (float*)smem + 4 * KK;
  if (lg == 0)
#pragma unroll
    for (int n = 0; n < 4; ++n) {
      totr[tw * KK + kw * 64 + n * 16 + lm] = carR[n];
      toti[tw * KK + kw * 64 + n * 16 + lm] = carI[n];
    }
  __syncthreads();
  float crR[4] = {0.f, 0.f, 0.f, 0.f}, crI[4] = {0.f, 0.f, 0.f, 0.f};
  for (int t2 = 0; t2 < tw; ++t2)
#pragma unroll
    for (int n = 0; n < 4; ++n) {
      crR[n] += totr[t2 * KK + kw * 64 + n * 16 + lm];
      crI[n] += toti[t2 * KK + kw * 64 + n * 16 + lm];
    }
  // ---- publish chunk aggregate (relaxed agent atomics -> memory-side, no inv)
  if (tw == 3 && lg == 0)
#pragma unroll
    for (int n = 0; n < 4; ++n) {
      int k = kw * 64 + n * 16 + lm;
      size_t idx = ((size_t)b * NCB + chunk) * KK + k;
      __hip_atomic_store(&csum_re[idx], crR[n] + carR[n], __ATOMIC_RELAXED, __HIP_MEMORY_SCOPE_AGENT);
      __hip_atomic_store(&csum_im[idx], crI[n] + carI[n], __ATOMIC_RELAXED, __HIP_MEMORY_SCOPE_AGENT);
    }

  // ---- manual grid barrier: 1 poller/block, relaxed polls, fence at edges only
  __syncthreads();
  if (tid == 0) {
    __threadfence();   // wb+inv local L2 once (publishes nothing stale, orders csum)
    __hip_atomic_fetch_add(counter, 1, __ATOMIC_RELAXED, __HIP_MEMORY_SCOPE_AGENT);
    while (__hip_atomic_load(counter, __ATOMIC_RELAXED, __HIP_MEMORY_SCOPE_AGENT) < NCB * BB)
      __builtin_amdgcn_s_sleep(4);
  }
  __syncthreads();

  // ---- look-back: sum predecessor aggregates (relaxed atomic loads, 4-way MLP)
  float* pre = (float*)smem + 2048;   // bytes 8192..9216, disjoint from totr/toti
  if (tid < 256) {
    float a0 = 0.f, a1 = 0.f, a2 = 0.f, a3 = 0.f;
    if (chunk > 0) {
      int v = tid & 127;
      float* srcp = (tid < 128) ? csum_re : csum_im;
      size_t base = (size_t)b * NCB * KK + v;
      int c = 0;
      for (; c + 4 <= chunk; c += 4) {
        a0 += __hip_atomic_load(&srcp[base + (size_t)(c + 0) * KK], __ATOMIC_RELAXED, __HIP_MEMORY_SCOPE_AGENT);
        a1 += __hip_atomic_load(&srcp[base + (size_t)(c + 1) * KK], __ATOMIC_RELAXED, __HIP_MEMORY_SCOPE_AGENT);
        a2 += __hip_atomic_load(&srcp[base + (size_t)(c + 2) * KK], __ATOMIC_RELAXED, __HIP_MEMORY_SCOPE_AGENT);
        a3 += __hip_atomic_load(&srcp[base + (size_t)(c + 3) * KK], __ATOMIC_RELAXED, __HIP_MEMORY_SCOPE_AGENT);
      }
      for (; c < chunk; ++c)
        a0 += __hip_atomic_load(&srcp[base + (size_t)c * KK], __ATOMIC_RELAXED, __HIP_MEMORY_SCOPE_AGENT);
    }
    pre[tid] = (a0 + a1) + (a2 + a3);
  }
  __syncthreads();

  // ---- add prefix, rotate by e^{-(alpha - i omega) ct}, emit C and S
#pragma unroll
  for (int m = 0; m < 2; ++m)
#pragma unroll
    for (int r = 0; r < 4; ++r) {
      size_t rowb = ((size_t)b * TT + t0 + tw * 32 + m * 16 + lg * 4 + r) * (2 * KK);
      float ctv_ = ctv[m][r];
#pragma unroll
      for (int n = 0; n < 4; ++n) {
        int k = kw * 64 + n * 16 + lm;
        float Sre = vre[m][n][r] + crR[n] + pre[k];
        float Sim = vim[m][n][r] + crI[n] + pre[KK + k];
        float dec = __expf(-pal[n] * ctv_);
        float sn, cs;
        __sincosf(pom[n] * ctv_, &sn, &cs);
        float Rw = dec * (cs * Sre - sn * Sim);
        float Iw = dec * (cs * Sim + sn * Sre);
        out[rowb + k] = Rw - Iw;        // C
        out[rowb + KK + k] = Rw + Iw;   // S
      }
    }
}

extern "C" void kernel_launch(void* const* d_in, const int* in_sizes, int n_in,
                              void* d_out, int out_size, void* d_ws, size_t ws_size,
                              hipStream_t stream) {
  const float* x    = (const float*)d_in[0];
  const float* dt   = (const float*)d_in[1];
  const float* srr  = (const float*)d_in[2];
  const float* si   = (const float*)d_in[3];
  const float* W    = (const float*)d_in[4];
  const float* bias = (const float*)d_in[5];
  const float* blog = (const float*)d_in[6];
  const float* usn  = (const float*)d_in[7];
  float* out = (float*)d_out;
  float* ws = (float*)d_ws;

  float* params  = ws;                          // 512 f
  float* ct      = ws + 4 * KK;                 // 65536 f
  float* csum_re = ct + (size_t)BB * TT;        // 65536 f
  float* csum_im = csum_re + (size_t)BB * NCB * KK;
  u16*   Wp      = (u16*)(csum_im + (size_t)BB * NCB * KK);  // 131072 u16
  int*   counter = (int*)(Wp + 131072);         // 1 int

  hipMemsetAsync(counter, 0, sizeof(int), stream);
  k_prep<<<81, 256, 0, stream>>>(W, usn, srr, si, bias, blog, dt, params, Wp, ct);
  k_fused<<<dim3(NCB, BB), 512, 0, stream>>>(x, Wp, dt, ct, params, out,
                                             csum_re, csum_im, counter);
}

// Round 6
// 102.070 us; speedup vs baseline: 1.5005x; 1.5005x over previous
//
#include <hip/hip_runtime.h>
#include <stdint.h>

#define BB 16
#define TT 4096
#define DDIM 512
#define KK 128
#define TCB 128            // t-rows per chunk
#define NCB (TT / TCB)     // 32 chunks
#define PI_F 3.14159265358979323846f

typedef unsigned short u16;
typedef __attribute__((ext_vector_type(8))) short short8;
typedef __attribute__((ext_vector_type(4))) float f32x4;

__device__ __forceinline__ uint32_t cvt_bf16_rn(float f) {
  uint32_t u = __float_as_uint(f);
  return (u + 0x7FFFu + ((u >> 16) & 1u)) >> 16;
}
__device__ __forceinline__ void split2(float a, float b, uint32_t& h, uint32_t& l) {
  uint32_t ha = cvt_bf16_rn(a), hb = cvt_bf16_rn(b);
  float ra = a - __uint_as_float(ha << 16);
  float rb = b - __uint_as_float(hb << 16);
  h = ha | (hb << 16);
  l = cvt_bf16_rn(ra) | (cvt_bf16_rn(rb) << 16);
}
__device__ __forceinline__ void split8v(const float4 f0, const float4 f1, uint4& h, uint4& l) {
  split2(f0.x, f0.y, h.x, l.x);
  split2(f0.z, f0.w, h.y, l.y);
  split2(f1.x, f1.y, h.z, l.z);
  split2(f1.z, f1.w, h.w, l.w);
}
__device__ __forceinline__ void gload_lds16(const void* g, void* l) {
  __builtin_amdgcn_global_load_lds(
      (const __attribute__((address_space(1))) void*)g,
      (__attribute__((address_space(3))) void*)l, 16, 0, 0);
}

// ---------------- kernel 0: fused prep (wpack | ct | params) ----------------
__global__ __launch_bounds__(256) void k_prep(
    const float* __restrict__ W, const float* __restrict__ u_sn,
    const float* __restrict__ s_real_raw, const float* __restrict__ s_imag,
    const float* __restrict__ bias, const float* __restrict__ b_log,
    const float* __restrict__ dt,
    float* __restrict__ params, u16* __restrict__ Wp, float* __restrict__ ct) {
  int gb = blockIdx.x;
  int tid = threadIdx.x;
  if (gb < 64) {
    int idx = gb * 256 + tid;
    int k = idx >> 7;
    int d = (idx & 127) * 4;
    float4 v = *(const float4*)&W[(size_t)k * DDIM + d];
    uint32_t h0, l0, h1, l1;
    split2(v.x, v.y, h0, l0);
    split2(v.z, v.w, h1, l1);
    int tile = d >> 6, dl = d & 63;
    int slot = (dl >> 3) ^ (k & 7);
    int e = dl & 7;
    size_t base = (size_t)tile * 16384 + k * 64 + slot * 8 + e;
    *(uint32_t*)&Wp[base] = h0;
    *(uint32_t*)&Wp[base + 2] = h1;
    *(uint32_t*)&Wp[base + 8192] = l0;
    *(uint32_t*)&Wp[base + 8192 + 2] = l1;
  } else if (gb < 80) {
    __shared__ float sc[256];
    int b = gb - 64;
    const float* row = dt + (size_t)b * TT;
    float* orow = ct + (size_t)b * TT;
    float loc[16];
    float s = 0.f;
    int base = tid * 16;
    for (int i = 0; i < 16; ++i) { s += row[base + i]; loc[i] = s; }
    sc[tid] = s;
    __syncthreads();
    for (int off = 1; off < 256; off <<= 1) {
      float v = (tid >= off) ? sc[tid - off] : 0.f;
      __syncthreads();
      sc[tid] += v;
      __syncthreads();
    }
    float excl = sc[tid] - s;
    for (int i = 0; i < 16; ++i) orow[base + i] = excl + loc[i];
  } else {
    __shared__ float su[KK];
    __shared__ float sv[DDIM];
    __shared__ float red[4];
    __shared__ float s_sig;
    if (tid < KK) su[tid] = u_sn[tid];
    __syncthreads();
    for (int rep = 0; rep < 2; ++rep) {
      int d = tid + rep * 256;
      float acc = 0.f;
      for (int k = 0; k < KK; ++k) acc += W[k * DDIM + d] * su[k];
      sv[d] = acc;
    }
    __syncthreads();
    float nn = 0.f;
    for (int rep = 0; rep < 2; ++rep) { float v = sv[tid + rep * 256]; nn += v * v; }
    for (int off = 32; off > 0; off >>= 1) nn += __shfl_down(nn, off, 64);
    if ((tid & 63) == 0) red[tid >> 6] = nn;
    __syncthreads();
    float vn2 = red[0] + red[1] + red[2] + red[3];
    __syncthreads();
    float vinv = 1.f / (sqrtf(vn2) + 1e-6f);
    for (int rep = 0; rep < 2; ++rep) sv[tid + rep * 256] *= vinv;
    __syncthreads();
    float wv = 0.f;
    if (tid < KK) {
      const float* wrow = W + (size_t)tid * DDIM;
      for (int d = 0; d < DDIM; ++d) wv += wrow[d] * sv[d];
    }
    float q = wv * wv;
    for (int off = 32; off > 0; off >>= 1) q += __shfl_down(q, off, 64);
    if ((tid & 63) == 0) red[tid >> 6] = q;
    __syncthreads();
    if (tid == 0) {
      float wn2 = red[0] + red[1] + red[2] + red[3];
      s_sig = wn2 / (sqrtf(wn2) + 1e-6f);
    }
    __syncthreads();
    if (tid < KK) {
      float inv_sigma = 1.f / s_sig;
      float sr = s_real_raw[tid];
      float alpha = ((sr > 20.f) ? sr : log1pf(expf(sr))) + 1e-6f;
      float om = fminf(fmaxf(s_imag[tid], -PI_F), PI_F);
      float bg = expf(b_log[tid]);
      params[tid] = alpha;
      params[KK + tid] = om;
      params[2 * KK + tid] = bg * inv_sigma;
      params[3 * KK + tid] = bg * bias[tid];
    }
  }
}

// ---------------- kernel 1: fused GEMM + reduce + grid-barrier + scan/finalize ----------------
// Cross-barrier live state: acc only (AGPR-residable). Transform is recomputed
// from acc post-barrier; wave totals persist in LDS across the barrier.
__global__ __launch_bounds__(512, 4) void k_fused(
    const float* __restrict__ x, const u16* __restrict__ Wp,
    const float* __restrict__ dt, const float* __restrict__ ct,
    const float* __restrict__ params, float* __restrict__ out,
    float* __restrict__ csum_re, float* __restrict__ csum_im,
    int* __restrict__ counter) {
  __shared__ __align__(16) u16 smem[32768];   // 64 KB
  u16* xhi = smem;            // [128][64]
  u16* xlo = smem + 8192;
  u16* whi = smem + 16384;    // [128][64]
  u16* wlo = smem + 24576;

  const int chunk = blockIdx.x, b = blockIdx.y;
  const int tid = threadIdx.x;
  const int wv = tid >> 6, l = tid & 63;
  const int lm = l & 15, lg = l >> 4;
  const int kw = wv & 1, tw = wv >> 1;
  const int t0 = chunk * TCB;

  const int xr = tid >> 2, xq = (tid & 3) * 16;
  const size_t xbase = ((size_t)b * TT + t0 + xr) * DDIM + xq;
  const char* wsrc0 = (const char*)Wp + (size_t)wv * 1024 + (size_t)l * 16;
  char* wdst0 = (char*)whi + wv * 1024;
  const int xs0 = ((xq >> 3) ^ (xr & 7)) * 8;
  const int xs1 = (((xq >> 3) + 1) ^ (xr & 7)) * 8;

  f32x4 acc[2][4];
#pragma unroll
  for (int m = 0; m < 2; ++m)
#pragma unroll
    for (int n = 0; n < 4; ++n) acc[m][n] = (f32x4)(0.0f);

  for (int d0 = 0; d0 < DDIM; d0 += 64) {
    const char* wsg = wsrc0 + (size_t)(d0 >> 6) * 32768;
#pragma unroll
    for (int r = 0; r < 4; ++r)
      gload_lds16(wsg + r * 8192, wdst0 + r * 8192);
    const float* xp = x + xbase + d0;
    float4 f0 = *(const float4*)(xp + 0);
    float4 f1 = *(const float4*)(xp + 4);
    float4 f2 = *(const float4*)(xp + 8);
    float4 f3 = *(const float4*)(xp + 12);
    uint4 h0, lo0, h1, lo1;
    split8v(f0, f1, h0, lo0);
    split8v(f2, f3, h1, lo1);
    *(uint4*)&xhi[xr * 64 + xs0] = h0;
    *(uint4*)&xhi[xr * 64 + xs1] = h1;
    *(uint4*)&xlo[xr * 64 + xs0] = lo0;
    *(uint4*)&xlo[xr * 64 + xs1] = lo1;
    __syncthreads();
#pragma unroll
    for (int ks = 0; ks < 2; ++ks) {
      short8 fa_h[2], fa_l[2], fb_h[4], fb_l[4];
#pragma unroll
      for (int m = 0; m < 2; ++m) {
        int row = tw * 32 + m * 16 + lm;
        int sw = ((ks * 4 + lg) ^ (row & 7)) * 8;
        fa_h[m] = *(const short8*)&xhi[row * 64 + sw];
        fa_l[m] = *(const short8*)&xlo[row * 64 + sw];
      }
#pragma unroll
      for (int n = 0; n < 4; ++n) {
        int row = kw * 64 + n * 16 + lm;
        int sw = ((ks * 4 + lg) ^ (row & 7)) * 8;
        fb_h[n] = *(const short8*)&whi[row * 64 + sw];
        fb_l[n] = *(const short8*)&wlo[row * 64 + sw];
      }
#pragma unroll
      for (int m = 0; m < 2; ++m)
#pragma unroll
        for (int n = 0; n < 4; ++n) {
          acc[m][n] = __builtin_amdgcn_mfma_f32_16x16x32_bf16(fa_h[m], fb_h[n], acc[m][n], 0, 0, 0);
          acc[m][n] = __builtin_amdgcn_mfma_f32_16x16x32_bf16(fa_l[m], fb_h[n], acc[m][n], 0, 0, 0);
          acc[m][n] = __builtin_amdgcn_mfma_f32_16x16x32_bf16(fa_h[m], fb_l[n], acc[m][n], 0, 0, 0);
        }
    }
    __syncthreads();
  }

  // ---- persistent LDS (survives the in-kernel barrier): wave totals + prefix
  float* totr = (float*)smem;          // [4][128]
  float* toti = (float*)smem + 512;    // [4][128]
  float* pre_ = (float*)smem + 1024;   // [256]

  float dtv[2][4], ctv[2][4];
#pragma unroll
  for (int m = 0; m < 2; ++m)
#pragma unroll
    for (int r = 0; r < 4; ++r) {
      int t = t0 + tw * 32 + m * 16 + lg * 4 + r;
      dtv[m][r] = dt[(size_t)b * TT + t];
      ctv[m][r] = ct[(size_t)b * TT + t];
    }

  // ---- pre-barrier: per-n transform + REDUCE to wave totals (no scan state kept)
#pragma unroll
  for (int n = 0; n < 4; ++n) {
    int k = kw * 64 + n * 16 + lm;
    float pal = params[k], pom = params[KK + k];
    float pc1 = params[2 * KK + k], pc2 = params[3 * KK + k];
    float sr = 0.f, si2 = 0.f;
#pragma unroll
    for (int m = 0; m < 2; ++m)
#pragma unroll
      for (int r = 0; r < 4; ++r) {
        float g = acc[m][n][r];
        float a = pal * dtv[m][r];
        float omr = a * (1.f - a * (0.5f - a * (1.f / 6.f)));  // 1 - exp(-a)
        float itv = omr * (pc1 * g + pc2);
        float e = __expf(pal * ctv[m][r]);
        float sn, cs;
        __sincosf(pom * ctv[m][r], &sn, &cs);
        sr += itv * e * cs;
        si2 -= itv * e * sn;
      }
    sr += __shfl_xor(sr, 16, 64);
    sr += __shfl_xor(sr, 32, 64);
    si2 += __shfl_xor(si2, 16, 64);
    si2 += __shfl_xor(si2, 32, 64);
    if (lg == 0) { totr[tw * KK + k] = sr; toti[tw * KK + k] = si2; }
  }
  __syncthreads();
  // ---- publish chunk totals (relaxed agent atomics, memory-side)
  if (tid < 256) {
    int v = tid & 127;
    float* src = (tid < 128) ? totr : toti;
    float* dst = (tid < 128) ? csum_re : csum_im;
    float tot = (src[v] + src[KK + v]) + (src[2 * KK + v] + src[3 * KK + v]);
    __hip_atomic_store(&dst[((size_t)b * NCB + chunk) * KK + v], tot,
                       __ATOMIC_RELAXED, __HIP_MEMORY_SCOPE_AGENT);
  }
  __syncthreads();
  // ---- grid barrier: 1 poller/block, relaxed polls
  if (tid == 0) {
    __threadfence();
    __hip_atomic_fetch_add(counter, 1, __ATOMIC_RELAXED, __HIP_MEMORY_SCOPE_AGENT);
    while (__hip_atomic_load(counter, __ATOMIC_RELAXED, __HIP_MEMORY_SCOPE_AGENT) < NCB * BB)
      __builtin_amdgcn_s_sleep(4);
  }
  __syncthreads();
  // ---- look-back: sum predecessor aggregates (relaxed, 4-way MLP)
  if (tid < 256) {
    float a0 = 0.f, a1 = 0.f, a2 = 0.f, a3 = 0.f;
    if (chunk > 0) {
      int v = tid & 127;
      float* srcp = (tid < 128) ? csum_re : csum_im;
      size_t base = (size_t)b * NCB * KK + v;
      int c = 0;
      for (; c + 4 <= chunk; c += 4) {
        a0 += __hip_atomic_load(&srcp[base + (size_t)(c + 0) * KK], __ATOMIC_RELAXED, __HIP_MEMORY_SCOPE_AGENT);
        a1 += __hip_atomic_load(&srcp[base + (size_t)(c + 1) * KK], __ATOMIC_RELAXED, __HIP_MEMORY_SCOPE_AGENT);
        a2 += __hip_atomic_load(&srcp[base + (size_t)(c + 2) * KK], __ATOMIC_RELAXED, __HIP_MEMORY_SCOPE_AGENT);
        a3 += __hip_atomic_load(&srcp[base + (size_t)(c + 3) * KK], __ATOMIC_RELAXED, __HIP_MEMORY_SCOPE_AGENT);
      }
      for (; c < chunk; ++c)
        a0 += __hip_atomic_load(&srcp[base + (size_t)c * KK], __ATOMIC_RELAXED, __HIP_MEMORY_SCOPE_AGENT);
    }
    pre_[tid] = (a0 + a1) + (a2 + a3);
  }
  __syncthreads();

  // ---- post-barrier: per-n recompute transform from acc, scan, rotate, store
#pragma unroll
  for (int n = 0; n < 4; ++n) {
    int k = kw * 64 + n * 16 + lm;
    float pal = params[k], pom = params[KK + k];
    float pc1 = params[2 * KK + k], pc2 = params[3 * KK + k];
    float cr = pre_[k], ci = pre_[KK + k];
    for (int t2 = 0; t2 < tw; ++t2) { cr += totr[t2 * KK + k]; ci += toti[t2 * KK + k]; }
#pragma unroll
    for (int m = 0; m < 2; ++m) {
      float vr[4], vi[4];
#pragma unroll
      for (int r = 0; r < 4; ++r) {
        float g = acc[m][n][r];
        float a = pal * dtv[m][r];
        float omr = a * (1.f - a * (0.5f - a * (1.f / 6.f)));
        float itv = omr * (pc1 * g + pc2);
        float e = __expf(pal * ctv[m][r]);
        float sn, cs;
        __sincosf(pom * ctv[m][r], &sn, &cs);
        vr[r] = itv * e * cs;
        vi[r] = -(itv * e) * sn;
      }
      vr[1] += vr[0]; vr[2] += vr[1]; vr[3] += vr[2];
      vi[1] += vi[0]; vi[2] += vi[1]; vi[3] += vi[2];
      float ar = vr[3], ai = vi[3];
      float tr0 = ar, ti0 = ai;
      float ur = __shfl_up(ar, 16, 64);
      float ui = __shfl_up(ai, 16, 64);
      if (lg >= 1) { ar += ur; ai += ui; }
      ur = __shfl_up(ar, 32, 64);
      ui = __shfl_up(ai, 32, 64);
      if (lg >= 2) { ar += ur; ai += ui; }
      float exr = ar - tr0 + cr;
      float exi = ai - ti0 + ci;
      cr += __shfl(ar, 48 + lm, 64);
      ci += __shfl(ai, 48 + lm, 64);
#pragma unroll
      for (int r = 0; r < 4; ++r) {
        float Sre = vr[r] + exr;
        float Sim = vi[r] + exi;
        float ctv_ = ctv[m][r];
        float dec = __expf(-pal * ctv_);
        float sn, cs;
        __sincosf(pom * ctv_, &sn, &cs);
        float Rw = dec * (cs * Sre - sn * Sim);
        float Iw = dec * (cs * Sim + sn * Sre);
        size_t rowb = ((size_t)b * TT + t0 + tw * 32 + m * 16 + lg * 4 + r) * (2 * KK);
        out[rowb + k] = Rw - Iw;        // C
        out[rowb + KK + k] = Rw + Iw;   // S
      }
    }
  }
}

extern "C" void kernel_launch(void* const* d_in, const int* in_sizes, int n_in,
                              void* d_out, int out_size, void* d_ws, size_t ws_size,
                              hipStream_t stream) {
  const float* x    = (const float*)d_in[0];
  const float* dt   = (const float*)d_in[1];
  const float* srr  = (const float*)d_in[2];
  const float* si   = (const float*)d_in[3];
  const float* W    = (const float*)d_in[4];
  const float* bias = (const float*)d_in[5];
  const float* blog = (const float*)d_in[6];
  const float* usn  = (const float*)d_in[7];
  float* out = (float*)d_out;
  float* ws = (float*)d_ws;

  float* params  = ws;                          // 512 f
  float* ct      = ws + 4 * KK;                 // 65536 f
  float* csum_re = ct + (size_t)BB * TT;        // 65536 f
  float* csum_im = csum_re + (size_t)BB * NCB * KK;
  u16*   Wp      = (u16*)(csum_im + (size_t)BB * NCB * KK);  // 131072 u16
  int*   counter = (int*)(Wp + 131072);         // 1 int

  hipMemsetAsync(counter, 0, sizeof(int), stream);
  k_prep<<<81, 256, 0, stream>>>(W, usn, srr, si, bias, blog, dt, params, Wp, ct);
  k_fused<<<dim3(NCB, BB), 512, 0, stream>>>(x, Wp, dt, ct, params, out,
                                             csum_re, csum_im, counter);
}

// Round 7
// 96.916 us; speedup vs baseline: 1.5803x; 1.0532x over previous
//
#include <hip/hip_runtime.h>
#include <stdint.h>

#define BB 16
#define TT 4096
#define DDIM 512
#define KK 128
#define TCB 128            // t-rows per chunk
#define NCB (TT / TCB)     // 32 chunks
#define PI_F 3.14159265358979323846f

typedef unsigned short u16;
typedef __attribute__((ext_vector_type(8))) short short8;
typedef __attribute__((ext_vector_type(4))) float f32x4;

__device__ __forceinline__ uint32_t cvt_bf16_rn(float f) {
  uint32_t u = __float_as_uint(f);
  return (u + 0x7FFFu + ((u >> 16) & 1u)) >> 16;
}
__device__ __forceinline__ uint32_t pack2(float a, float b) {
  return cvt_bf16_rn(a) | (cvt_bf16_rn(b) << 16);
}
__device__ __forceinline__ uint4 pack8(const float4 f0, const float4 f1) {
  uint4 r;
  r.x = pack2(f0.x, f0.y);
  r.y = pack2(f0.z, f0.w);
  r.z = pack2(f1.x, f1.y);
  r.w = pack2(f1.z, f1.w);
  return r;
}
__device__ __forceinline__ void gload_lds16(const void* g, void* l) {
  __builtin_amdgcn_global_load_lds(
      (const __attribute__((address_space(1))) void*)g,
      (__attribute__((address_space(3))) void*)l, 16, 0, 0);
}

// ---------------- kernel 0: fused prep (wpack | ct | params) ----------------
__global__ __launch_bounds__(256) void k_prep(
    const float* __restrict__ W, const float* __restrict__ u_sn,
    const float* __restrict__ s_real_raw, const float* __restrict__ s_imag,
    const float* __restrict__ bias, const float* __restrict__ b_log,
    const float* __restrict__ dt,
    float* __restrict__ params, u16* __restrict__ Wp, float* __restrict__ ct) {
  int gb = blockIdx.x;
  int tid = threadIdx.x;
  if (gb < 64) {
    // single-bf16 W image, pre-swizzled per 64-d tile:
    // idx = tile*8192 + k*64 + ((dl>>3)^(k&7))*8 + (dl&7)
    int idx = gb * 256 + tid;
    int k = idx >> 7;
    int d = (idx & 127) * 4;
    float4 v = *(const float4*)&W[(size_t)k * DDIM + d];
    int tile = d >> 6, dl = d & 63;
    int slot = (dl >> 3) ^ (k & 7);
    int e = dl & 7;  // 0 or 4
    size_t base = (size_t)tile * 8192 + k * 64 + slot * 8 + e;
    uint2 p;
    p.x = pack2(v.x, v.y);
    p.y = pack2(v.z, v.w);
    *(uint2*)&Wp[base] = p;
  } else if (gb < 80) {
    __shared__ float sc[256];
    int b = gb - 64;
    const float* row = dt + (size_t)b * TT;
    float* orow = ct + (size_t)b * TT;
    float loc[16];
    float s = 0.f;
    int base = tid * 16;
    for (int i = 0; i < 16; ++i) { s += row[base + i]; loc[i] = s; }
    sc[tid] = s;
    __syncthreads();
    for (int off = 1; off < 256; off <<= 1) {
      float v = (tid >= off) ? sc[tid - off] : 0.f;
      __syncthreads();
      sc[tid] += v;
      __syncthreads();
    }
    float excl = sc[tid] - s;
    for (int i = 0; i < 16; ++i) orow[base + i] = excl + loc[i];
  } else {
    __shared__ float su[KK];
    __shared__ float sv[DDIM];
    __shared__ float red[4];
    __shared__ float s_sig;
    if (tid < KK) su[tid] = u_sn[tid];
    __syncthreads();
    for (int rep = 0; rep < 2; ++rep) {
      int d = tid + rep * 256;
      float acc = 0.f;
      for (int k = 0; k < KK; ++k) acc += W[k * DDIM + d] * su[k];
      sv[d] = acc;
    }
    __syncthreads();
    float nn = 0.f;
    for (int rep = 0; rep < 2; ++rep) { float v = sv[tid + rep * 256]; nn += v * v; }
    for (int off = 32; off > 0; off >>= 1) nn += __shfl_down(nn, off, 64);
    if ((tid & 63) == 0) red[tid >> 6] = nn;
    __syncthreads();
    float vn2 = red[0] + red[1] + red[2] + red[3];
    __syncthreads();
    float vinv = 1.f / (sqrtf(vn2) + 1e-6f);
    for (int rep = 0; rep < 2; ++rep) sv[tid + rep * 256] *= vinv;
    __syncthreads();
    float wv = 0.f;
    if (tid < KK) {
      const float* wrow = W + (size_t)tid * DDIM;
      for (int d = 0; d < DDIM; ++d) wv += wrow[d] * sv[d];
    }
    float q = wv * wv;
    for (int off = 32; off > 0; off >>= 1) q += __shfl_down(q, off, 64);
    if ((tid & 63) == 0) red[tid >> 6] = q;
    __syncthreads();
    if (tid == 0) {
      float wn2 = red[0] + red[1] + red[2] + red[3];
      s_sig = wn2 / (sqrtf(wn2) + 1e-6f);
    }
    __syncthreads();
    if (tid < KK) {
      float inv_sigma = 1.f / s_sig;
      float sr = s_real_raw[tid];
      float alpha = ((sr > 20.f) ? sr : log1pf(expf(sr))) + 1e-6f;
      float om = fminf(fmaxf(s_imag[tid], -PI_F), PI_F);
      float bg = expf(b_log[tid]);
      params[tid] = alpha;
      params[KK + tid] = om;
      params[2 * KK + tid] = bg * inv_sigma;
      params[3 * KK + tid] = bg * bias[tid];
    }
  }
}

// ---------------- kernel 1: pipelined GEMM + reduce + grid-barrier + scan/finalize ----------------
// Single-bf16 MFMA (error budget: adds ~1.3e-5 to output, threshold 3.4e-4).
// Double-buffered LDS (x 2x16KB + W 2x16KB = 64KB); per-iter: issue next-tile
// loads -> sched_barrier -> MFMA on cur -> sched_barrier -> convert+ds_write -> 1 barrier.
__global__ __launch_bounds__(512, 4) void k_fused(
    const float* __restrict__ x, const u16* __restrict__ Wp,
    const float* __restrict__ dt, const float* __restrict__ ct,
    const float* __restrict__ params, float* __restrict__ out,
    float* __restrict__ csum_re, float* __restrict__ csum_im,
    int* __restrict__ counter) {
  __shared__ __align__(16) u16 smem[32768];   // 64 KB
  // u16 offsets: xb0 @0, xb1 @8192, wb0 @16384, wb1 @24576 (each 128 rows x 64)

  const int chunk = blockIdx.x, b = blockIdx.y;
  const int tid = threadIdx.x;
  const int wv = tid >> 6, l = tid & 63;
  const int lm = l & 15, lg = l >> 4;
  const int kw = wv & 1, tw = wv >> 1;
  const int t0 = chunk * TCB;

  const int xr = tid >> 2, xq = (tid & 3) * 16;
  const size_t xbase = ((size_t)b * TT + t0 + xr) * DDIM + xq;
  const int xs0 = ((xq >> 3) ^ (xr & 7)) * 8;
  const int xs1 = (((xq >> 3) + 1) ^ (xr & 7)) * 8;

  f32x4 acc[2][4];
#pragma unroll
  for (int m = 0; m < 2; ++m)
#pragma unroll
    for (int n = 0; n < 4; ++n) acc[m][n] = (f32x4)(0.0f);

  // ---- prologue: stage tile 0 into buffer 0
  {
    const char* wsg = (const char*)Wp + (size_t)tid * 16;
    char* wd = (char*)smem + 32768 + tid * 16;
    gload_lds16(wsg, wd);
    gload_lds16(wsg + 8192, wd + 8192);
    const float* xp = x + xbase;
    float4 f0 = *(const float4*)(xp + 0);
    float4 f1 = *(const float4*)(xp + 4);
    float4 f2 = *(const float4*)(xp + 8);
    float4 f3 = *(const float4*)(xp + 12);
    *(uint4*)&smem[xr * 64 + xs0] = pack8(f0, f1);
    *(uint4*)&smem[xr * 64 + xs1] = pack8(f2, f3);
  }
  __syncthreads();

  int cur = 0;
  for (int it = 0; it < 8; ++it) {
    float4 f0, f1, f2, f3;
    // ---- phase 1: issue next-tile loads (x -> regs, W -> LDS via DMA)
    if (it < 7) {
      const float* xp = x + xbase + (it + 1) * 64;
      f0 = *(const float4*)(xp + 0);
      f1 = *(const float4*)(xp + 4);
      f2 = *(const float4*)(xp + 8);
      f3 = *(const float4*)(xp + 12);
      const char* wsg = (const char*)Wp + (size_t)(it + 1) * 16384 + tid * 16;
      char* wd = (char*)smem + 32768 + (cur ^ 1) * 16384 + tid * 16;
      gload_lds16(wsg, wd);
      gload_lds16(wsg + 8192, wd + 8192);
    }
    __builtin_amdgcn_sched_barrier(0);
    // ---- phase 2: MFMA on current buffers
    {
      const u16* xb = smem + cur * 8192;
      const u16* wb = smem + 16384 + cur * 8192;
#pragma unroll
      for (int ks = 0; ks < 2; ++ks) {
        short8 fa[2], fb[4];
#pragma unroll
        for (int m = 0; m < 2; ++m) {
          int row = tw * 32 + m * 16 + lm;
          int sw = ((ks * 4 + lg) ^ (row & 7)) * 8;
          fa[m] = *(const short8*)&xb[row * 64 + sw];
        }
#pragma unroll
        for (int n = 0; n < 4; ++n) {
          int row = kw * 64 + n * 16 + lm;
          int sw = ((ks * 4 + lg) ^ (row & 7)) * 8;
          fb[n] = *(const short8*)&wb[row * 64 + sw];
        }
#pragma unroll
        for (int m = 0; m < 2; ++m)
#pragma unroll
          for (int n = 0; n < 4; ++n)
            acc[m][n] = __builtin_amdgcn_mfma_f32_16x16x32_bf16(fa[m], fb[n], acc[m][n], 0, 0, 0);
      }
    }
    __builtin_amdgcn_sched_barrier(0);
    // ---- phase 3: convert prefetched x, write to next buffer
    if (it < 7) {
      u16* xb = smem + (cur ^ 1) * 8192;
      *(uint4*)&xb[xr * 64 + xs0] = pack8(f0, f1);
      *(uint4*)&xb[xr * 64 + xs1] = pack8(f2, f3);
    }
    __syncthreads();
    cur ^= 1;
  }

  // ---- persistent LDS (survives the in-kernel grid barrier)
  float* totr = (float*)smem;          // [4][128]
  float* toti = (float*)smem + 512;    // [4][128]
  float* pre_ = (float*)smem + 1024;   // [256]

  float dtv[2][4], ctv[2][4];
#pragma unroll
  for (int m = 0; m < 2; ++m)
#pragma unroll
    for (int r = 0; r < 4; ++r) {
      int t = t0 + tw * 32 + m * 16 + lg * 4 + r;
      dtv[m][r] = dt[(size_t)b * TT + t];
      ctv[m][r] = ct[(size_t)b * TT + t];
    }

  // ---- pre-barrier: per-n transform + REDUCE to wave totals
#pragma unroll
  for (int n = 0; n < 4; ++n) {
    int k = kw * 64 + n * 16 + lm;
    float pal = params[k], pom = params[KK + k];
    float pc1 = params[2 * KK + k], pc2 = params[3 * KK + k];
    float sr = 0.f, si2 = 0.f;
#pragma unroll
    for (int m = 0; m < 2; ++m)
#pragma unroll
      for (int r = 0; r < 4; ++r) {
        float g = acc[m][n][r];
        float a = pal * dtv[m][r];
        float omr = a * (1.f - a * (0.5f - a * (1.f / 6.f)));  // 1 - exp(-a)
        float itv = omr * (pc1 * g + pc2);
        float e = __expf(pal * ctv[m][r]);
        float sn, cs;
        __sincosf(pom * ctv[m][r], &sn, &cs);
        sr += itv * e * cs;
        si2 -= itv * e * sn;
      }
    sr += __shfl_xor(sr, 16, 64);
    sr += __shfl_xor(sr, 32, 64);
    si2 += __shfl_xor(si2, 16, 64);
    si2 += __shfl_xor(si2, 32, 64);
    if (lg == 0) { totr[tw * KK + k] = sr; toti[tw * KK + k] = si2; }
  }
  __syncthreads();
  // ---- publish chunk totals (relaxed agent atomics)
  if (tid < 256) {
    int v = tid & 127;
    float* src = (tid < 128) ? totr : toti;
    float* dst = (tid < 128) ? csum_re : csum_im;
    float tot = (src[v] + src[KK + v]) + (src[2 * KK + v] + src[3 * KK + v]);
    __hip_atomic_store(&dst[((size_t)b * NCB + chunk) * KK + v], tot,
                       __ATOMIC_RELAXED, __HIP_MEMORY_SCOPE_AGENT);
  }
  __syncthreads();
  // ---- grid barrier: 1 poller/block, relaxed polls
  if (tid == 0) {
    __threadfence();
    __hip_atomic_fetch_add(counter, 1, __ATOMIC_RELAXED, __HIP_MEMORY_SCOPE_AGENT);
    while (__hip_atomic_load(counter, __ATOMIC_RELAXED, __HIP_MEMORY_SCOPE_AGENT) < NCB * BB)
      __builtin_amdgcn_s_sleep(4);
  }
  __syncthreads();
  // ---- look-back: sum predecessor aggregates
  if (tid < 256) {
    float a0 = 0.f, a1 = 0.f, a2 = 0.f, a3 = 0.f;
    if (chunk > 0) {
      int v = tid & 127;
      float* srcp = (tid < 128) ? csum_re : csum_im;
      size_t base = (size_t)b * NCB * KK + v;
      int c = 0;
      for (; c + 4 <= chunk; c += 4) {
        a0 += __hip_atomic_load(&srcp[base + (size_t)(c + 0) * KK], __ATOMIC_RELAXED, __HIP_MEMORY_SCOPE_AGENT);
        a1 += __hip_atomic_load(&srcp[base + (size_t)(c + 1) * KK], __ATOMIC_RELAXED, __HIP_MEMORY_SCOPE_AGENT);
        a2 += __hip_atomic_load(&srcp[base + (size_t)(c + 2) * KK], __ATOMIC_RELAXED, __HIP_MEMORY_SCOPE_AGENT);
        a3 += __hip_atomic_load(&srcp[base + (size_t)(c + 3) * KK], __ATOMIC_RELAXED, __HIP_MEMORY_SCOPE_AGENT);
      }
      for (; c < chunk; ++c)
        a0 += __hip_atomic_load(&srcp[base + (size_t)c * KK], __ATOMIC_RELAXED, __HIP_MEMORY_SCOPE_AGENT);
    }
    pre_[tid] = (a0 + a1) + (a2 + a3);
  }
  __syncthreads();

  // ---- post-barrier: recompute transform from acc, scan, rotate, store
#pragma unroll
  for (int n = 0; n < 4; ++n) {
    int k = kw * 64 + n * 16 + lm;
    float pal = params[k], pom = params[KK + k];
    float pc1 = params[2 * KK + k], pc2 = params[3 * KK + k];
    float cr = pre_[k], ci = pre_[KK + k];
    for (int t2 = 0; t2 < tw; ++t2) { cr += totr[t2 * KK + k]; ci += toti[t2 * KK + k]; }
#pragma unroll
    for (int m = 0; m < 2; ++m) {
      float vr[4], vi[4], e4[4], sn4[4], cs4[4];
#pragma unroll
      for (int r = 0; r < 4; ++r) {
        float g = acc[m][n][r];
        float a = pal * dtv[m][r];
        float omr = a * (1.f - a * (0.5f - a * (1.f / 6.f)));
        float itv = omr * (pc1 * g + pc2);
        float e = __expf(pal * ctv[m][r]);
        float sn, cs;
        __sincosf(pom * ctv[m][r], &sn, &cs);
        e4[r] = e; sn4[r] = sn; cs4[r] = cs;
        vr[r] = itv * e * cs;
        vi[r] = -(itv * e) * sn;
      }
      vr[1] += vr[0]; vr[2] += vr[1]; vr[3] += vr[2];
      vi[1] += vi[0]; vi[2] += vi[1]; vi[3] += vi[2];
      float ar = vr[3], ai = vi[3];
      float tr0 = ar, ti0 = ai;
      float ur = __shfl_up(ar, 16, 64);
      float ui = __shfl_up(ai, 16, 64);
      if (lg >= 1) { ar += ur; ai += ui; }
      ur = __shfl_up(ar, 32, 64);
      ui = __shfl_up(ai, 32, 64);
      if (lg >= 2) { ar += ur; ai += ui; }
      float exr = ar - tr0 + cr;
      float exi = ai - ti0 + ci;
      cr += __shfl(ar, 48 + lm, 64);
      ci += __shfl(ai, 48 + lm, 64);
#pragma unroll
      for (int r = 0; r < 4; ++r) {
        float Sre = vr[r] + exr;
        float Sim = vi[r] + exi;
        float dec = __builtin_amdgcn_rcpf(e4[r]);   // e^{-alpha*ct} = 1/e
        float sn = sn4[r], cs = cs4[r];
        float Rw = dec * (cs * Sre - sn * Sim);
        float Iw = dec * (cs * Sim + sn * Sre);
        size_t rowb = ((size_t)b * TT + t0 + tw * 32 + m * 16 + lg * 4 + r) * (2 * KK);
        out[rowb + k] = Rw - Iw;        // C
        out[rowb + KK + k] = Rw + Iw;   // S
      }
    }
  }
}

extern "C" void kernel_launch(void* const* d_in, const int* in_sizes, int n_in,
                              void* d_out, int out_size, void* d_ws, size_t ws_size,
                              hipStream_t stream) {
  const float* x    = (const float*)d_in[0];
  const float* dt   = (const float*)d_in[1];
  const float* srr  = (const float*)d_in[2];
  const float* si   = (const float*)d_in[3];
  const float* W    = (const float*)d_in[4];
  const float* bias = (const float*)d_in[5];
  const float* blog = (const float*)d_in[6];
  const float* usn  = (const float*)d_in[7];
  float* out = (float*)d_out;
  float* ws = (float*)d_ws;

  float* params  = ws;                          // 512 f
  float* ct      = ws + 4 * KK;                 // 65536 f
  float* csum_re = ct + (size_t)BB * TT;        // 65536 f
  float* csum_im = csum_re + (size_t)BB * NCB * KK;
  u16*   Wp      = (u16*)(csum_im + (size_t)BB * NCB * KK);  // 65536 u16 (128 KB)
  int*   counter = (int*)(Wp + 65536);          // 1 int

  hipMemsetAsync(counter, 0, sizeof(int), stream);
  k_prep<<<81, 256, 0, stream>>>(W, usn, srr, si, bias, blog, dt, params, Wp, ct);
  k_fused<<<dim3(NCB, BB), 512, 0, stream>>>(x, Wp, dt, ct, params, out,
                                             csum_re, csum_im, counter);
}

// Round 8
// 76.414 us; speedup vs baseline: 2.0043x; 1.2683x over previous
//
#include <hip/hip_runtime.h>
#include <stdint.h>

#define BB 16
#define TT 4096
#define DDIM 512
#define KK 128
#define TCB 128            // t-rows per chunk
#define NCB (TT / TCB)     // 32 chunks
#define PI_F 3.14159265358979323846f

typedef unsigned short u16;
typedef __attribute__((ext_vector_type(8))) short short8;
typedef __attribute__((ext_vector_type(4))) float f32x4;

__device__ __forceinline__ uint32_t cvt_bf16_rn(float f) {
  uint32_t u = __float_as_uint(f);
  return (u + 0x7FFFu + ((u >> 16) & 1u)) >> 16;
}
__device__ __forceinline__ uint32_t pack2(float a, float b) {
  return cvt_bf16_rn(a) | (cvt_bf16_rn(b) << 16);
}
__device__ __forceinline__ uint4 pack8(const float4 f0, const float4 f1) {
  uint4 r;
  r.x = pack2(f0.x, f0.y);
  r.y = pack2(f0.z, f0.w);
  r.z = pack2(f1.x, f1.y);
  r.w = pack2(f1.z, f1.w);
  return r;
}
__device__ __forceinline__ void gload_lds16(const void* g, void* l) {
  __builtin_amdgcn_global_load_lds(
      (const __attribute__((address_space(1))) void*)g,
      (__attribute__((address_space(3))) void*)l, 16, 0, 0);
}
#define AT_LD(p) __hip_atomic_load((p), __ATOMIC_RELAXED, __HIP_MEMORY_SCOPE_AGENT)
#define AT_ST(p, v) __hip_atomic_store((p), (v), __ATOMIC_RELAXED, __HIP_MEMORY_SCOPE_AGENT)

// ---------------- kernel 0: fused prep (wpack | ct | params) ----------------
__global__ __launch_bounds__(256) void k_prep(
    const float* __restrict__ W, const float* __restrict__ u_sn,
    const float* __restrict__ s_real_raw, const float* __restrict__ s_imag,
    const float* __restrict__ bias, const float* __restrict__ b_log,
    const float* __restrict__ dt,
    float* __restrict__ params, u16* __restrict__ Wp, float* __restrict__ ct) {
  int gb = blockIdx.x;
  int tid = threadIdx.x;
  if (gb < 64) {
    // single-bf16 W image, pre-swizzled per 64-d tile:
    // idx = tile*8192 + k*64 + ((dl>>3)^(k&7))*8 + (dl&7)
    int idx = gb * 256 + tid;
    int k = idx >> 7;
    int d = (idx & 127) * 4;
    float4 v = *(const float4*)&W[(size_t)k * DDIM + d];
    int tile = d >> 6, dl = d & 63;
    int slot = (dl >> 3) ^ (k & 7);
    int e = dl & 7;  // 0 or 4
    size_t base = (size_t)tile * 8192 + k * 64 + slot * 8 + e;
    uint2 p;
    p.x = pack2(v.x, v.y);
    p.y = pack2(v.z, v.w);
    *(uint2*)&Wp[base] = p;
  } else if (gb < 80) {
    __shared__ float sc[256];
    int b = gb - 64;
    const float* row = dt + (size_t)b * TT;
    float* orow = ct + (size_t)b * TT;
    float loc[16];
    float s = 0.f;
    int base = tid * 16;
    for (int i = 0; i < 16; ++i) { s += row[base + i]; loc[i] = s; }
    sc[tid] = s;
    __syncthreads();
    for (int off = 1; off < 256; off <<= 1) {
      float v = (tid >= off) ? sc[tid - off] : 0.f;
      __syncthreads();
      sc[tid] += v;
      __syncthreads();
    }
    float excl = sc[tid] - s;
    for (int i = 0; i < 16; ++i) orow[base + i] = excl + loc[i];
  } else {
    __shared__ float su[KK];
    __shared__ float sv[DDIM];
    __shared__ float red[4];
    __shared__ float s_sig;
    if (tid < KK) su[tid] = u_sn[tid];
    __syncthreads();
    for (int rep = 0; rep < 2; ++rep) {
      int d = tid + rep * 256;
      float acc = 0.f;
      for (int k = 0; k < KK; ++k) acc += W[k * DDIM + d] * su[k];
      sv[d] = acc;
    }
    __syncthreads();
    float nn = 0.f;
    for (int rep = 0; rep < 2; ++rep) { float v = sv[tid + rep * 256]; nn += v * v; }
    for (int off = 32; off > 0; off >>= 1) nn += __shfl_down(nn, off, 64);
    if ((tid & 63) == 0) red[tid >> 6] = nn;
    __syncthreads();
    float vn2 = red[0] + red[1] + red[2] + red[3];
    __syncthreads();
    float vinv = 1.f / (sqrtf(vn2) + 1e-6f);
    for (int rep = 0; rep < 2; ++rep) sv[tid + rep * 256] *= vinv;
    __syncthreads();
    float wv = 0.f;
    if (tid < KK) {
      const float* wrow = W + (size_t)tid * DDIM;
      for (int d = 0; d < DDIM; ++d) wv += wrow[d] * sv[d];
    }
    float q = wv * wv;
    for (int off = 32; off > 0; off >>= 1) q += __shfl_down(q, off, 64);
    if ((tid & 63) == 0) red[tid >> 6] = q;
    __syncthreads();
    if (tid == 0) {
      float wn2 = red[0] + red[1] + red[2] + red[3];
      s_sig = wn2 / (sqrtf(wn2) + 1e-6f);
    }
    __syncthreads();
    if (tid < KK) {
      float inv_sigma = 1.f / s_sig;
      float sr = s_real_raw[tid];
      float alpha = ((sr > 20.f) ? sr : log1pf(expf(sr))) + 1e-6f;
      float om = fminf(fmaxf(s_imag[tid], -PI_F), PI_F);
      float bg = expf(b_log[tid]);
      params[tid] = alpha;
      params[KK + tid] = om;
      params[2 * KK + tid] = bg * inv_sigma;
      params[3 * KK + tid] = bg * bias[tid];
    }
  }
}

// ---------------- kernel 1: pipelined GEMM + reduce + per-b sync + scan/finalize ----------------
// Sync redesign: per-b counter (chunk-0 block is the designated prefixer, converts
// csum totals -> exclusive prefixes in place), flag2[b] released after; other
// blocks only poll flag2 and read their single prefix row. ~30x fewer
// serialized cross-XCD atomics than all-blocks-scan-all-predecessors.
__global__ __launch_bounds__(512, 4) void k_fused(
    const float* __restrict__ x, const u16* __restrict__ Wp,
    const float* __restrict__ dt, const float* __restrict__ ct,
    const float* __restrict__ params, float* __restrict__ out,
    float* __restrict__ csum_re, float* __restrict__ csum_im,
    int* __restrict__ cnt) {
  __shared__ __align__(16) u16 smem[32768];   // 64 KB
  // u16 offsets: xb0 @0, xb1 @8192, wb0 @16384, wb1 @24576

  const int chunk = blockIdx.x, b = blockIdx.y;
  const int tid = threadIdx.x;
  const int wv = tid >> 6, l = tid & 63;
  const int lm = l & 15, lg = l >> 4;
  const int kw = wv & 1, tw = wv >> 1;
  const int t0 = chunk * TCB;

  const int xr = tid >> 2, xq = (tid & 3) * 16;
  const size_t xbase = ((size_t)b * TT + t0 + xr) * DDIM + xq;
  const int xs0 = ((xq >> 3) ^ (xr & 7)) * 8;
  const int xs1 = (((xq >> 3) + 1) ^ (xr & 7)) * 8;

  f32x4 acc[2][4];
#pragma unroll
  for (int m = 0; m < 2; ++m)
#pragma unroll
    for (int n = 0; n < 4; ++n) acc[m][n] = (f32x4)(0.0f);

  // ---- prologue: stage tile 0 into buffer 0
  {
    const char* wsg = (const char*)Wp + (size_t)tid * 16;
    char* wd = (char*)smem + 32768 + tid * 16;
    gload_lds16(wsg, wd);
    gload_lds16(wsg + 8192, wd + 8192);
    const float* xp = x + xbase;
    float4 f0 = *(const float4*)(xp + 0);
    float4 f1 = *(const float4*)(xp + 4);
    float4 f2 = *(const float4*)(xp + 8);
    float4 f3 = *(const float4*)(xp + 12);
    *(uint4*)&smem[xr * 64 + xs0] = pack8(f0, f1);
    *(uint4*)&smem[xr * 64 + xs1] = pack8(f2, f3);
  }
  __syncthreads();

  int cur = 0;
  for (int it = 0; it < 8; ++it) {
    float4 f0, f1, f2, f3;
    // ---- phase 1: issue next-tile loads (x -> regs, W -> LDS via DMA)
    if (it < 7) {
      const float* xp = x + xbase + (it + 1) * 64;
      f0 = *(const float4*)(xp + 0);
      f1 = *(const float4*)(xp + 4);
      f2 = *(const float4*)(xp + 8);
      f3 = *(const float4*)(xp + 12);
      const char* wsg = (const char*)Wp + (size_t)(it + 1) * 16384 + tid * 16;
      char* wd = (char*)smem + 32768 + (cur ^ 1) * 16384 + tid * 16;
      gload_lds16(wsg, wd);
      gload_lds16(wsg + 8192, wd + 8192);
    }
    __builtin_amdgcn_sched_barrier(0);
    // ---- phase 2: MFMA on current buffers
    {
      const u16* xb = smem + cur * 8192;
      const u16* wb = smem + 16384 + cur * 8192;
#pragma unroll
      for (int ks = 0; ks < 2; ++ks) {
        short8 fa[2], fb[4];
#pragma unroll
        for (int m = 0; m < 2; ++m) {
          int row = tw * 32 + m * 16 + lm;
          int sw = ((ks * 4 + lg) ^ (row & 7)) * 8;
          fa[m] = *(const short8*)&xb[row * 64 + sw];
        }
#pragma unroll
        for (int n = 0; n < 4; ++n) {
          int row = kw * 64 + n * 16 + lm;
          int sw = ((ks * 4 + lg) ^ (row & 7)) * 8;
          fb[n] = *(const short8*)&wb[row * 64 + sw];
        }
#pragma unroll
        for (int m = 0; m < 2; ++m)
#pragma unroll
          for (int n = 0; n < 4; ++n)
            acc[m][n] = __builtin_amdgcn_mfma_f32_16x16x32_bf16(fa[m], fb[n], acc[m][n], 0, 0, 0);
      }
    }
    __builtin_amdgcn_sched_barrier(0);
    // ---- phase 3: convert prefetched x, write to next buffer
    if (it < 7) {
      u16* xb = smem + (cur ^ 1) * 8192;
      *(uint4*)&xb[xr * 64 + xs0] = pack8(f0, f1);
      *(uint4*)&xb[xr * 64 + xs1] = pack8(f2, f3);
    }
    __syncthreads();
    cur ^= 1;
  }

  // ---- persistent LDS (survives the sync phase)
  float* totr = (float*)smem;          // [4][128]
  float* toti = (float*)smem + 512;    // [4][128]
  float* pre_ = (float*)smem + 1024;   // [256]

  float dtv[2][4], ctv[2][4];
#pragma unroll
  for (int m = 0; m < 2; ++m)
#pragma unroll
    for (int r = 0; r < 4; ++r) {
      int t = t0 + tw * 32 + m * 16 + lg * 4 + r;
      dtv[m][r] = dt[(size_t)b * TT + t];
      ctv[m][r] = ct[(size_t)b * TT + t];
    }

  // ---- pre-sync: per-n transform + REDUCE to wave totals
#pragma unroll
  for (int n = 0; n < 4; ++n) {
    int k = kw * 64 + n * 16 + lm;
    float pal = params[k], pom = params[KK + k];
    float pc1 = params[2 * KK + k], pc2 = params[3 * KK + k];
    float sr = 0.f, si2 = 0.f;
#pragma unroll
    for (int m = 0; m < 2; ++m)
#pragma unroll
      for (int r = 0; r < 4; ++r) {
        float g = acc[m][n][r];
        float a = pal * dtv[m][r];
        float omr = a * (1.f - a * (0.5f - a * (1.f / 6.f)));  // 1 - exp(-a)
        float itv = omr * (pc1 * g + pc2);
        float e = __expf(pal * ctv[m][r]);
        float sn, cs;
        __sincosf(pom * ctv[m][r], &sn, &cs);
        sr += itv * e * cs;
        si2 -= itv * e * sn;
      }
    sr += __shfl_xor(sr, 16, 64);
    sr += __shfl_xor(sr, 32, 64);
    si2 += __shfl_xor(si2, 16, 64);
    si2 += __shfl_xor(si2, 32, 64);
    if (lg == 0) { totr[tw * KK + k] = sr; toti[tw * KK + k] = si2; }
  }
  __syncthreads();
  // ---- publish chunk totals (relaxed agent atomics)
  if (tid < 256) {
    int v = tid & 127;
    float* src = (tid < 128) ? totr : toti;
    float* dst = (tid < 128) ? csum_re : csum_im;
    float tot = (src[v] + src[KK + v]) + (src[2 * KK + v] + src[3 * KK + v]);
    AT_ST(&dst[((size_t)b * NCB + chunk) * KK + v], tot);
  }
  __syncthreads();
  if (tid == 0) {
    __threadfence();
    __hip_atomic_fetch_add(&cnt[b * 64], 1, __ATOMIC_RELAXED, __HIP_MEMORY_SCOPE_AGENT);
  }

  // ---- designated prefixer: chunk-0 block turns totals into exclusive prefixes
  if (chunk == 0) {
    if (tid == 0)
      while (AT_LD(&cnt[b * 64]) < NCB) __builtin_amdgcn_s_sleep(2);
    __syncthreads();
    if (tid < 256) {
      int v = tid & 127;
      float* srcp = (tid < 128) ? csum_re : csum_im;
      size_t base = (size_t)b * NCB * KK + v;
      float vals[NCB];
#pragma unroll
      for (int c = 0; c < NCB; ++c) vals[c] = AT_LD(&srcp[base + (size_t)c * KK]);
      float run = 0.f;
#pragma unroll
      for (int c = 0; c < NCB; ++c) { float t = vals[c]; AT_ST(&srcp[base + (size_t)c * KK], run); run += t; }
    }
    __syncthreads();
    if (tid == 0) {
      __threadfence();
      AT_ST(&cnt[b * 64 + 32], 1);
    }
  }
  // ---- all blocks: wait for prefixes, read own row
  if (tid == 0)
    while (AT_LD(&cnt[b * 64 + 32]) == 0) __builtin_amdgcn_s_sleep(2);
  __syncthreads();
  if (tid < 256) {
    int v = tid & 127;
    float* srcp = (tid < 128) ? csum_re : csum_im;
    pre_[tid] = AT_LD(&srcp[((size_t)b * NCB + chunk) * KK + v]);
  }
  __syncthreads();

  // ---- post-sync: recompute transform from acc, scan, rotate, store
#pragma unroll
  for (int n = 0; n < 4; ++n) {
    int k = kw * 64 + n * 16 + lm;
    float pal = params[k], pom = params[KK + k];
    float pc1 = params[2 * KK + k], pc2 = params[3 * KK + k];
    float cr = pre_[k], ci = pre_[KK + k];
    for (int t2 = 0; t2 < tw; ++t2) { cr += totr[t2 * KK + k]; ci += toti[t2 * KK + k]; }
#pragma unroll
    for (int m = 0; m < 2; ++m) {
      float vr[4], vi[4], e4[4], sn4[4], cs4[4];
#pragma unroll
      for (int r = 0; r < 4; ++r) {
        float g = acc[m][n][r];
        float a = pal * dtv[m][r];
        float omr = a * (1.f - a * (0.5f - a * (1.f / 6.f)));
        float itv = omr * (pc1 * g + pc2);
        float e = __expf(pal * ctv[m][r]);
        float sn, cs;
        __sincosf(pom * ctv[m][r], &sn, &cs);
        e4[r] = e; sn4[r] = sn; cs4[r] = cs;
        vr[r] = itv * e * cs;
        vi[r] = -(itv * e) * sn;
      }
      vr[1] += vr[0]; vr[2] += vr[1]; vr[3] += vr[2];
      vi[1] += vi[0]; vi[2] += vi[1]; vi[3] += vi[2];
      float ar = vr[3], ai = vi[3];
      float tr0 = ar, ti0 = ai;
      float ur = __shfl_up(ar, 16, 64);
      float ui = __shfl_up(ai, 16, 64);
      if (lg >= 1) { ar += ur; ai += ui; }
      ur = __shfl_up(ar, 32, 64);
      ui = __shfl_up(ai, 32, 64);
      if (lg >= 2) { ar += ur; ai += ui; }
      float exr = ar - tr0 + cr;
      float exi = ai - ti0 + ci;
      cr += __shfl(ar, 48 + lm, 64);
      ci += __shfl(ai, 48 + lm, 64);
#pragma unroll
      for (int r = 0; r < 4; ++r) {
        float Sre = vr[r] + exr;
        float Sim = vi[r] + exi;
        float dec = __builtin_amdgcn_rcpf(e4[r]);   // e^{-alpha*ct} = 1/e
        float sn = sn4[r], cs = cs4[r];
        float Rw = dec * (cs * Sre - sn * Sim);
        float Iw = dec * (cs * Sim + sn * Sre);
        size_t rowb = ((size_t)b * TT + t0 + tw * 32 + m * 16 + lg * 4 + r) * (2 * KK);
        out[rowb + k] = Rw - Iw;        // C
        out[rowb + KK + k] = Rw + Iw;   // S
      }
    }
  }
}

extern "C" void kernel_launch(void* const* d_in, const int* in_sizes, int n_in,
                              void* d_out, int out_size, void* d_ws, size_t ws_size,
                              hipStream_t stream) {
  const float* x    = (const float*)d_in[0];
  const float* dt   = (const float*)d_in[1];
  const float* srr  = (const float*)d_in[2];
  const float* si   = (const float*)d_in[3];
  const float* W    = (const float*)d_in[4];
  const float* bias = (const float*)d_in[5];
  const float* blog = (const float*)d_in[6];
  const float* usn  = (const float*)d_in[7];
  float* out = (float*)d_out;
  float* ws = (float*)d_ws;

  float* params  = ws;                          // 512 f
  float* ct      = ws + 4 * KK;                 // 65536 f
  float* csum_re = ct + (size_t)BB * TT;        // 65536 f
  float* csum_im = csum_re + (size_t)BB * NCB * KK;
  u16*   Wp      = (u16*)(csum_im + (size_t)BB * NCB * KK);  // 65536 u16 (128 KB)
  int*   cnt     = (int*)(Wp + 65536);          // 16*64 ints (counter + flag2, padded)

  hipMemsetAsync(cnt, 0, 16 * 64 * sizeof(int), stream);
  k_prep<<<81, 256, 0, stream>>>(W, usn, srr, si, bias, blog, dt, params, Wp, ct);
  k_fused<<<dim3(NCB, BB), 512, 0, stream>>>(x, Wp, dt, ct, params, out,
                                             csum_re, csum_im, cnt);
}